// Round 1
// baseline (2211.568 us; speedup 1.0000x reference)
//
#include <hip/hip_runtime.h>

#define N_ROWS 1024
#define D_DIM  1024
#define V_DIM  32000
#define KF     8
#define K_TOT  (KF * D_DIM)   // 8192

#define BM 128
#define BN 128
#define BK 64

typedef __attribute__((ext_vector_type(8))) __bf16 bf16x8;
typedef __attribute__((ext_vector_type(4))) float  f32x4;

// f32 -> bf16 RNE (bit trick, ~3 VALU ops)
__device__ __forceinline__ ushort f2bf(float f) {
    union { float f; unsigned u; } c; c.f = f;
    unsigned r = (c.u + 0x7fffu + ((c.u >> 16) & 1u)) >> 16;
    return (ushort)r;
}

__device__ __forceinline__ void global_to_lds16(const void* gp, void* lp) {
    __builtin_amdgcn_global_load_lds(
        (__attribute__((address_space(1))) void*)gp,
        (__attribute__((address_space(3))) void*)lp, 16, 0, 0);
}

// ---------------- Kernel 1: gate softmax + Y = g*x (bf16) ----------------
// grid: N_ROWS blocks x 256 threads; thread t owns d = 4t..4t+3
__global__ __launch_bounds__(256)
void gate_y_kernel(const float* __restrict__ x, const float* __restrict__ Wg,
                   const float* __restrict__ bg, ushort* __restrict__ Y,
                   float* __restrict__ g_out, float* __restrict__ fb_out)
{
    const int n = blockIdx.x;
    const int t = threadIdx.x;
    float4 xv = ((const float4*)(x + (size_t)n * D_DIM))[t];
    float p[KF];
#pragma unroll
    for (int k = 0; k < KF; ++k) {
        float4 wv = ((const float4*)(Wg + k * D_DIM))[t];
        p[k] = xv.x * wv.x + xv.y * wv.y + xv.z * wv.z + xv.w * wv.w;
    }
#pragma unroll
    for (int k = 0; k < KF; ++k) {
        float v = p[k];
#pragma unroll
        for (int off = 32; off > 0; off >>= 1) v += __shfl_down(v, off, 64);
        p[k] = v;
    }
    __shared__ float part[4][KF];
    const int wave = t >> 6, lane = t & 63;
    if (lane == 0) {
#pragma unroll
        for (int k = 0; k < KF; ++k) part[wave][k] = p[k];
    }
    __syncthreads();
    float s[KF], mx = -1e30f;
#pragma unroll
    for (int k = 0; k < KF; ++k) {
        s[k] = part[0][k] + part[1][k] + part[2][k] + part[3][k] + bg[k];
        mx = fmaxf(mx, s[k]);
    }
    float sum = 0.f;
#pragma unroll
    for (int k = 0; k < KF; ++k) { s[k] = expf(s[k] - mx); sum += s[k]; }
    float inv = 1.0f / sum;
#pragma unroll
    for (int k = 0; k < KF; ++k) s[k] *= inv;
    if (t < KF) g_out[n * KF + t] = s[t];
    // facet_balance: softmax rows sum to 1 exactly => (mean(g)-1/KF)^2 ~ 1e-14 ~= 0
    if (n == 0 && t == 0) fb_out[0] = 0.0f;
#pragma unroll
    for (int k = 0; k < KF; ++k) {
        ushort4 u;
        u.x = f2bf(s[k] * xv.x);
        u.y = f2bf(s[k] * xv.y);
        u.z = f2bf(s[k] * xv.z);
        u.w = f2bf(s[k] * xv.w);
        ((ushort4*)(Y + (size_t)n * K_TOT + k * D_DIM))[t] = u;
    }
}

// ---------------- Kernel 2: out = Y @ B^T + g@bf ----------------
// B^T[v, k*D+d] = Wf[k,v,d]; 128x128 tile, BK=64, 4 waves 2x2, 4x4 frags
// LDS layout: [row][slot] 16B chunks, slot = kgroup ^ (row&7)  (bank swizzle)
__global__ __launch_bounds__(256)
void moe_gemm_kernel(const ushort* __restrict__ Y, const float* __restrict__ Wf,
                     const float* __restrict__ bfv, const float* __restrict__ g,
                     float* __restrict__ out)
{
    __shared__ ushort ldsA[BM * BK];   // 16 KB
    __shared__ ushort ldsB[BN * BK];   // 16 KB
    const int t = threadIdx.x;
    const int lane = t & 63;
    const int w = t >> 6;
    const int wm = w >> 1, wn = w & 1;
    const int m0 = blockIdx.x * BM;
    const int v0 = blockIdx.y * BN;
    const int cl = lane & 15, q = lane >> 4;

    f32x4 acc[4][4] = {};

    for (int kb = 0; kb < K_TOT; kb += BK) {
        const int kf  = kb >> 10;          // facet index (BK divides D)
        const int dof = kb & (D_DIM - 1);  // d-offset within facet
        // ---- A stage: Y (bf16) via global_load_lds, source-side swizzle ----
#pragma unroll
        for (int r = 0; r < 4; ++r) {
            int c = r * 256 + w * 64 + lane;     // 16B chunk id, 0..1023
            int row = c >> 3, sl = c & 7;
            int kg = sl ^ (row & 7);
            const ushort* gp = Y + (size_t)(m0 + row) * K_TOT + kb + kg * 8;
            global_to_lds16(gp, &ldsA[c * 8]);
        }
        // ---- B stage: Wf f32 -> bf16 convert -> ds_write (swizzled) ----
        const float* wb = Wf + (size_t)kf * V_DIM * D_DIM + dof;
#pragma unroll
        for (int r = 0; r < 8; ++r) {
            int f = r * 256 + t;                 // float4 id over [v][16]
            int v = f >> 4, kk4 = f & 15;
            float4 wv = *(const float4*)(wb + (size_t)(v0 + v) * D_DIM + kk4 * 4);
            ushort4 u;
            u.x = f2bf(wv.x); u.y = f2bf(wv.y); u.z = f2bf(wv.z); u.w = f2bf(wv.w);
            int kg = kk4 >> 1, hf = kk4 & 1;
            *(ushort4*)&ldsB[v * BK + ((kg ^ (v & 7)) * 8 + hf * 4)] = u;
        }
        __syncthreads();
        // ---- compute: 2 k-steps x 4x4 MFMA ----
#pragma unroll
        for (int ks = 0; ks < 2; ++ks) {
            bf16x8 af[4], bg8[4];
#pragma unroll
            for (int i = 0; i < 4; ++i) {
                int row = wm * 64 + i * 16 + cl;
                int kg = ks * 4 + q;
                af[i] = *(const bf16x8*)&ldsA[row * BK + (kg ^ (row & 7)) * 8];
            }
#pragma unroll
            for (int j = 0; j < 4; ++j) {
                int col = wn * 64 + j * 16 + cl;
                int kg = ks * 4 + q;
                bg8[j] = *(const bf16x8*)&ldsB[col * BK + (kg ^ (col & 7)) * 8];
            }
#pragma unroll
            for (int i = 0; i < 4; ++i)
#pragma unroll
                for (int j = 0; j < 4; ++j)
                    acc[i][j] = __builtin_amdgcn_mfma_f32_16x16x32_bf16(
                        af[i], bg8[j], acc[i][j], 0, 0, 0);
        }
        __syncthreads();
    }

    // ---- epilogue: out = acc + g[n,:] . bf[:,v] ----
    float* bfs = (float*)ldsA;   // [KF][BN]
    float* gsl = (float*)ldsB;   // [BM][KF]
    {
        int k = t >> 5, c = (t & 31) * 4;
        float4 bv = *(const float4*)(bfv + (size_t)k * V_DIM + v0 + c);
        *(float4*)&bfs[k * BN + c] = bv;
        int row = t >> 1, kq = (t & 1) * 4;
        float4 gv = *(const float4*)(g + (size_t)(m0 + row) * KF + kq);
        *(float4*)&gsl[row * KF + kq] = gv;
    }
    __syncthreads();
    float bcol[4][KF];
#pragma unroll
    for (int j = 0; j < 4; ++j) {
        int col = wn * 64 + j * 16 + cl;
#pragma unroll
        for (int k = 0; k < KF; ++k) bcol[j][k] = bfs[k * BN + col];
    }
#pragma unroll
    for (int i = 0; i < 4; ++i) {
#pragma unroll
        for (int e = 0; e < 4; ++e) {
            int row = wm * 64 + i * 16 + q * 4 + e;   // C/D: col=lane&15, row=q*4+reg
            f32x4 g0 = *(const f32x4*)&gsl[row * KF];
            f32x4 g1 = *(const f32x4*)&gsl[row * KF + 4];
#pragma unroll
            for (int j = 0; j < 4; ++j) {
                float b = g0.x * bcol[j][0] + g0.y * bcol[j][1] + g0.z * bcol[j][2] + g0.w * bcol[j][3]
                        + g1.x * bcol[j][4] + g1.y * bcol[j][5] + g1.z * bcol[j][6] + g1.w * bcol[j][7];
                out[(size_t)(m0 + row) * V_DIM + v0 + wn * 64 + j * 16 + cl] = acc[i][j][e] + b;
            }
        }
    }
}

extern "C" void kernel_launch(void* const* d_in, const int* in_sizes, int n_in,
                              void* d_out, int out_size, void* d_ws, size_t ws_size,
                              hipStream_t stream)
{
    const float* x   = (const float*)d_in[0];
    const float* Wg  = (const float*)d_in[1];
    const float* bg  = (const float*)d_in[2];
    const float* Wf  = (const float*)d_in[3];
    const float* bfv = (const float*)d_in[4];
    float* out = (float*)d_out;

    ushort* Y = (ushort*)d_ws;                                   // 16 MB bf16
    float*  g = (float*)((char*)d_ws + (size_t)N_ROWS * K_TOT * 2); // 32 KB

    gate_y_kernel<<<N_ROWS, 256, 0, stream>>>(x, Wg, bg, Y, g,
                                              out + (size_t)N_ROWS * V_DIM);
    dim3 grid(N_ROWS / BM, V_DIM / BN);
    moe_gemm_kernel<<<grid, 256, 0, stream>>>(Y, Wf, bfv, g, out);
}